// Round 16
// baseline (712.019 us; speedup 1.0000x reference)
//
#include <hip/hip_runtime.h>
#include <hip/hip_bf16.h>
#include <stdint.h>

#define NROWS 32768   // 32*32*32
#define NCODE 4096
#define CDIM  256
#define KDIM  1024
#define NSLOT 96
#define MARGIN 1.0f

typedef __attribute__((ext_vector_type(8))) short bf16x8;
typedef __attribute__((ext_vector_type(4))) float f32x4;

static __device__ __forceinline__ unsigned f2ord(float f) {
    unsigned b = __float_as_uint(f);
    return (b & 0x80000000u) ? ~b : (b | 0x80000000u);
}
static __device__ __forceinline__ float ord2f(unsigned u) {
    unsigned b = (u & 0x80000000u) ? (u ^ 0x80000000u) : ~u;
    return __uint_as_float(b);
}
static __device__ __forceinline__ unsigned short to_bf16(float f) {
    __hip_bfloat16 h = __float2bfloat16(f);
    return *(unsigned short*)&h;
}
// pure compiler fence: no instructions emitted, blocks memory-op reordering
static __device__ __forceinline__ void cfence() {
    __builtin_amdgcn_sched_barrier(0);
    asm volatile("" ::: "memory");
}

// ---------------- kernel 1: e = codebook @ proj_w^T + proj_b  (fp32 exact) --
extern "C" __global__ __launch_bounds__(256)
void k_proj(const float* __restrict__ cb, const float* __restrict__ pw,
            const float* __restrict__ pb, float* __restrict__ e,
            unsigned short* __restrict__ eb)
{
    __shared__ __align__(16) float As[32][68];
    __shared__ __align__(16) float Bs[32][68];
    const int tid = threadIdx.x;
    const int tx = tid & 15, ty = tid >> 4;
    const int bm = blockIdx.x;
    const int bn = blockIdx.y;
    float acc[4][4] = {};

    float4 pva[2], pvb[2];
    auto issueP = [&](int k0) {
#pragma unroll
        for (int i = 0; i < 2; ++i) {
            int idx = tid + i * 256;
            int row = idx >> 3;
            int kg  = (idx & 7) << 2;
            pva[i] = *(const float4*)(cb + (size_t)(bm * 64 + row) * KDIM + k0 + kg);
            pvb[i] = *(const float4*)(pw + (size_t)(bn * 64 + row) * KDIM + k0 + kg);
        }
    };

    issueP(0);
    for (int k0 = 0; k0 < KDIM; k0 += 32) {
#pragma unroll
        for (int i = 0; i < 2; ++i) {          // commit regs -> LDS (transpose)
            int idx = tid + i * 256;
            int row = idx >> 3;
            int kg  = (idx & 7) << 2;
            As[kg + 0][row] = pva[i].x; As[kg + 1][row] = pva[i].y;
            As[kg + 2][row] = pva[i].z; As[kg + 3][row] = pva[i].w;
            Bs[kg + 0][row] = pvb[i].x; Bs[kg + 1][row] = pvb[i].y;
            Bs[kg + 2][row] = pvb[i].z; Bs[kg + 3][row] = pvb[i].w;
        }
        __syncthreads();
        if (k0 + 32 < KDIM) issueP(k0 + 32);   // overlap with compute below
#pragma unroll
        for (int k = 0; k < 32; ++k) {
            float4 a = *(const float4*)&As[k][ty * 4];
            float4 b = *(const float4*)&Bs[k][tx * 4];
            float av[4] = {a.x, a.y, a.z, a.w};
            float bv[4] = {b.x, b.y, b.z, b.w};
#pragma unroll
            for (int i = 0; i < 4; ++i)
#pragma unroll
                for (int j = 0; j < 4; ++j)
                    acc[i][j] = fmaf(av[i], bv[j], acc[i][j]);
        }
        __syncthreads();
    }
    const int col0 = bn * 64 + tx * 4;
    float4 bias = *(const float4*)(pb + col0);
    float bb[4] = {bias.x, bias.y, bias.z, bias.w};
#pragma unroll
    for (int i = 0; i < 4; ++i) {
        int row = bm * 64 + ty * 4 + i;
        float o[4];
#pragma unroll
        for (int j = 0; j < 4; ++j) o[j] = acc[i][j] + bb[j];
        *(float4*)(e + (size_t)row * CDIM + col0) = make_float4(o[0], o[1], o[2], o[3]);
        ushort4 ob;
        ob.x = to_bf16(o[0]); ob.y = to_bf16(o[1]);
        ob.z = to_bf16(o[2]); ob.w = to_bf16(o[3]);
        *(ushort4*)(eb + (size_t)row * CDIM + col0) = ob;
    }
}

// ---------------- kernel 1b: ||e_j||^2 ----------------
extern "C" __global__ __launch_bounds__(256)
void k_enorm(const float* __restrict__ e, float* __restrict__ en)
{
    int code = blockIdx.x * 4 + (threadIdx.x >> 6);
    int lane = threadIdx.x & 63;
    float4 v = *(const float4*)(e + (size_t)code * CDIM + lane * 4);
    float s = v.x * v.x + v.y * v.y + v.z * v.z + v.w * v.w;
#pragma unroll
    for (int off = 1; off < 64; off <<= 1) s += __shfl_xor(s, off);
    if (lane == 0) en[code] = s;
}

// ---------------- kernel 1d: z -> bf16 + zero cnt (merged init) -------------
extern "C" __global__ __launch_bounds__(256)
void k_cvtz(const float* __restrict__ z, unsigned short* __restrict__ zb,
            unsigned* __restrict__ cnt)
{
    size_t i = (size_t)blockIdx.x * 256 + threadIdx.x;   // 16 floats / thread
    if (i < NROWS) cnt[i] = 0u;
    const float4* src = (const float4*)(z + i * 16);
    unsigned short o[16];
#pragma unroll
    for (int q = 0; q < 4; ++q) {
        float4 v = src[q];
        o[q * 4 + 0] = to_bf16(v.x); o[q * 4 + 1] = to_bf16(v.y);
        o[q * 4 + 2] = to_bf16(v.z); o[q * 4 + 3] = to_bf16(v.w);
    }
    *(uint4*)(zb + i * 16)     = *(const uint4*)&o[0];   // 16 B
    *(uint4*)(zb + i * 16 + 8) = *(const uint4*)&o[8];   // 16 B
}

// ---------------- kernel 2: bf16 MFMA score + block argmin + candidates -----
// 256x128 tile, 512 threads (8 waves as 4x2, 64x64 out each), K-step 32,
// counted-vmcnt double-buffer with compiler fences (r15-proven sync).
// LDS/buf: A 16K + B 8K; x2 buffers + 1K rowmin = 50,176B -> 3 blocks/CU
// (24 waves/CU).  Per thread per step: 3 global_load_lds (vs r15's 4), B
// panel reused by 2x the rows.  Swizzle FIXED to ((row>>1)&3)<<4: within a
// 16-row b128 read group each 16B slot gets exactly 2 lanes -> 2-way = free
// (r15's (row&3) gave 4-way, 8.4M conflicts).  Same XOR staged on the
// inverse-swizzled global source (rule #21).
extern "C" __global__ __launch_bounds__(512, 6)
void k_dist(const unsigned short* __restrict__ zb, const unsigned short* __restrict__ eb,
            const float* __restrict__ en, unsigned* __restrict__ cnt,
            unsigned* __restrict__ cand)
{
    __shared__ __align__(16) char lds[49152];     // [buf][A 16K | B 8K]
    __shared__ unsigned rowmin[256];
    const int tid  = threadIdx.x;
    const int wave = tid >> 6, lane = tid & 63;
    const int bC = blockIdx.x, bR = blockIdx.y;   // grid (32, 128)
    const int wr = wave >> 1, wc = wave & 1;      // 4x2 waves
    const int fr = lane & 15;                     // A row / B col within frag
    const int kb = (lane >> 4) << 4;              // k byte offset: 0,16,32,48
    if (tid < 256) rowmin[tid] = 0xFFFFFFFFu;

    const char* gz = (const char*)zb + (size_t)bR * 256 * 512;  // row = 512B
    const char* ge = (const char*)eb + (size_t)bC * 128 * 512;

    auto STAGE = [&](int s, int buf) {            // 3 gload_lds / thread
#pragma unroll
        for (int i = 0; i < 2; ++i) {             // A: 1024 chunks
            int chunk = tid + i * 512;
            int r  = chunk >> 2;                  // 0..255
            int wb = (chunk & 3) << 4;
            int sw = wb ^ (((r >> 1) & 3) << 4);  // inverse-swizzled source
            const char* gA = gz + (size_t)r * 512 + s * 64 + sw;
            char* lA = lds + buf * 24576 + i * 8192 + wave * 1024;
            __builtin_amdgcn_global_load_lds(
                (const __attribute__((address_space(1))) unsigned int*)gA,
                (__attribute__((address_space(3))) unsigned int*)lA, 16, 0, 0);
        }
        {                                         // B: 512 chunks
            int chunk = tid;
            int r  = chunk >> 2;                  // 0..127
            int wb = (chunk & 3) << 4;
            int sw = wb ^ (((r >> 1) & 3) << 4);
            const char* gB = ge + (size_t)r * 512 + s * 64 + sw;
            char* lB = lds + buf * 24576 + 16384 + wave * 1024;
            __builtin_amdgcn_global_load_lds(
                (const __attribute__((address_space(1))) unsigned int*)gB,
                (__attribute__((address_space(3))) unsigned int*)lB, 16, 0, 0);
        }
    };

    // epilogue constants prefetched early
    const int colg0 = bC * 128 + wc * 64;
    float env[4];
#pragma unroll
    for (int ni = 0; ni < 4; ++ni) env[ni] = en[colg0 + ni * 16 + fr];

    f32x4 acc[4][4] = {};

    STAGE(0, 0);
#pragma unroll
    for (int s = 0; s < 8; ++s) {                 // K-step 32: k in [s*32, +32)
        const int cur = s & 1;
        if (s < 7) {
            STAGE(s + 1, cur ^ 1);                // issue next (3 in flight)
            asm volatile("s_waitcnt vmcnt(3)" ::: "memory");  // drain s only
        } else {
            asm volatile("s_waitcnt vmcnt(0)" ::: "memory");
        }
        cfence();
        __builtin_amdgcn_s_barrier();             // buf cur complete for all
        cfence();
        const char* As = lds + cur * 24576;
        const char* Bs = As + 16384;
        bf16x8 a[4], b[4];
#pragma unroll
        for (int mi = 0; mi < 4; ++mi) {
            int row = wr * 64 + mi * 16 + fr;
            a[mi] = *(const bf16x8*)(As + row * 64 + (kb ^ (((row >> 1) & 3) << 4)));
        }
#pragma unroll
        for (int ni = 0; ni < 4; ++ni) {
            int row = wc * 64 + ni * 16 + fr;
            b[ni] = *(const bf16x8*)(Bs + row * 64 + (kb ^ (((row >> 1) & 3) << 4)));
        }
#pragma unroll
        for (int mi = 0; mi < 4; ++mi)
#pragma unroll
            for (int ni = 0; ni < 4; ++ni)
                acc[mi][ni] = __builtin_amdgcn_mfma_f32_16x16x32_bf16(
                    a[mi], b[ni], acc[mi][ni], 0, 0, 0);
        cfence();
        __builtin_amdgcn_s_barrier();             // reads done before re-stage
        cfence();
    }

    // ---- epilogue: d~ = en[col] - 2*s ; block-local row minima ----
#pragma unroll
    for (int mi = 0; mi < 4; ++mi)
#pragma unroll
        for (int ni = 0; ni < 4; ++ni)
#pragma unroll
            for (int j = 0; j < 4; ++j)
                acc[mi][ni][j] = fmaf(-2.0f, acc[mi][ni][j], env[ni]);

#pragma unroll
    for (int mi = 0; mi < 4; ++mi) {
#pragma unroll
        for (int j = 0; j < 4; ++j) {
            unsigned best = 0xFFFFFFFFu;
#pragma unroll
            for (int ni = 0; ni < 4; ++ni) {
                unsigned o = f2ord(acc[mi][ni][j]);
                best = o < best ? o : best;
            }
#pragma unroll
            for (int off = 8; off >= 1; off >>= 1) {
                unsigned o = __shfl_xor(best, off);
                best = o < best ? o : best;
            }
            if (fr == 0) {
                int rl = wr * 64 + mi * 16 + ((lane >> 4) << 2) + j;
                atomicMin(&rowmin[rl], best);
            }
        }
    }
    __syncthreads();

    // ---- emission: every col within MARGIN of block-local row min.
    //      NaN-safe: !(x > thr) is TRUE for NaN -> mass-emit -> fallback.
#pragma unroll
    for (int mi = 0; mi < 4; ++mi) {
#pragma unroll
        for (int j = 0; j < 4; ++j) {
            int rl = wr * 64 + mi * 16 + ((lane >> 4) << 2) + j;
            float thr = ord2f(rowmin[rl]) + MARGIN;
#pragma unroll
            for (int ni = 0; ni < 4; ++ni) {
                if (!(acc[mi][ni][j] > thr)) {
                    int rg = bR * 256 + rl;
                    unsigned slot = atomicAdd(&cnt[rg], 1u);
                    if (slot < NSLOT)
                        cand[(size_t)rg * NSLOT + slot] =
                            (unsigned)(colg0 + ni * 16 + fr);
                }
            }
        }
    }
}

// ---------------- kernel 3: exact re-rank, 4 candidates in parallel ---------
extern "C" __global__ __launch_bounds__(256)
void k_rerank(const float* __restrict__ z, const float* __restrict__ e,
              const float* __restrict__ en, const unsigned* __restrict__ cnt,
              const unsigned* __restrict__ cand, unsigned* __restrict__ outidx)
{
    int row  = blockIdx.x * 4 + (threadIdx.x >> 6);
    int lane = threadIdx.x & 63;
    int g    = lane >> 4;           // which of the 4 parallel candidates
    int sl   = lane & 15;           // sub-lane: dims [sl*16, sl*16+16)
    const float* zp = z + (size_t)row * CDIM + sl * 16;
    float4 zv[4];
#pragma unroll
    for (int t = 0; t < 4; ++t) zv[t] = *(const float4*)(zp + t * 4);
    unsigned n = cnt[row];
    double best_d2 = 1e300;
    unsigned best_col = 0u;

    auto eval4 = [&](unsigned col, bool valid) {
        const float* ep = e + (size_t)col * CDIM + sl * 16;
        double dot = 0.0;
#pragma unroll
        for (int t = 0; t < 4; ++t) {
            float4 ev = *(const float4*)(ep + t * 4);
            dot += (double)zv[t].x * ev.x + (double)zv[t].y * ev.y
                 + (double)zv[t].z * ev.z + (double)zv[t].w * ev.w;
        }
#pragma unroll
        for (int off = 1; off < 16; off <<= 1) dot += __shfl_xor(dot, off);
        double d2 = valid ? ((double)en[col] - 2.0 * dot) : 1e300;
#pragma unroll
        for (int off = 16; off <= 32; off <<= 1) {
            double od2    = __shfl_xor(d2, off);
            unsigned ocol = (unsigned)__shfl_xor((int)col, off);
            if (od2 < d2 || (od2 == d2 && ocol < col)) { d2 = od2; col = ocol; }
        }
        if (d2 < best_d2 || (d2 == best_d2 && col < best_col)) {
            best_d2 = d2; best_col = col;
        }
    };

    if (n >= 1u && n <= (unsigned)NSLOT) {
        for (unsigned i = 0; i < n; i += 4) {
            unsigned ii = i + (unsigned)g;
            bool valid = ii < n;
            unsigned col = valid ? (cand[(size_t)row * NSLOT + ii] & (NCODE - 1)) : 0u;
            eval4(col, valid);
        }
    } else {
        for (unsigned c0 = 0; c0 < NCODE; c0 += 4)
            eval4(c0 + (unsigned)g, true);
    }
    if (lane == 0) outidx[row] = best_col;
}

// ---------------- kernel 4: zidx + quant gather (overwrites ALL of d_out) ---
extern "C" __global__ __launch_bounds__(256)
void k_out(const unsigned* __restrict__ outidx, const float* __restrict__ e,
           float* __restrict__ out)
{
    int row  = blockIdx.x * 4 + (threadIdx.x >> 6);
    int lane = threadIdx.x & 63;
    unsigned idx = outidx[row] & (NCODE - 1);
    if (lane == 0) out[row] = (float)idx;
    float4 v = *(const float4*)(e + (size_t)idx * CDIM + lane * 4);
    *(float4*)(out + NROWS + (size_t)row * CDIM + lane * 4) = v;
}

extern "C" void kernel_launch(void* const* d_in, const int* in_sizes, int n_in,
                              void* d_out, int out_size, void* d_ws, size_t ws_size,
                              hipStream_t stream)
{
    const float* encode = (const float*)d_in[0];   // 32768 x 256
    const float* cb     = (const float*)d_in[1];   // 4096 x 1024
    const float* pw     = (const float*)d_in[2];   // 256 x 1024
    const float* pb     = (const float*)d_in[3];   // 256
    float* out = (float*)d_out;

    // ws: only what k_rerank/k_out read while d_out is being rewritten.
    char* ws = (char*)d_ws;
    float*    e      = (float*)(ws);                                  // 4 MiB
    float*    en     = (float*)(ws + (4u << 20));                     // 16 KiB
    unsigned* cnt    = (unsigned*)(ws + (4u << 20) + (16u << 10));    // 128 KiB
    unsigned* outidx = (unsigned*)(ws + (4u << 20) + (144u << 10));   // 128 KiB

    // Big transients in d_out's quant region (scratch until k_out's final
    // full overwrite; nothing reads them after k_rerank).
    char* S = (char*)(out + NROWS);
    unsigned short* zb   = (unsigned short*)(S);               // 16 MiB
    unsigned short* eb   = (unsigned short*)(S + (16u << 20)); // 2 MiB
    unsigned*       cand = (unsigned*)(S + (18u << 20));       // 12 MiB (ends 30 MiB)

    k_proj  <<<dim3(64, 4),   256, 0, stream>>>(cb, pw, pb, e, eb);
    k_enorm <<<dim3(1024),    256, 0, stream>>>(e, en);
    k_cvtz  <<<dim3(2048),    256, 0, stream>>>(encode, zb, cnt);
    k_dist  <<<dim3(32, 128), 512, 0, stream>>>(zb, eb, en, cnt, cand);
    k_rerank<<<dim3(8192),    256, 0, stream>>>(encode, e, en, cnt, cand, outidx);
    k_out   <<<dim3(8192),    256, 0, stream>>>(outidx, e, out);
}

// Round 17
// 364.258 us; speedup vs baseline: 1.9547x; 1.9547x over previous
//
#include <hip/hip_runtime.h>
#include <hip/hip_bf16.h>
#include <stdint.h>

#define NROWS 32768   // 32*32*32
#define NCODE 4096
#define CDIM  256
#define KDIM  1024
#define NSLOT 96
#define MARGIN 1.0f

typedef __attribute__((ext_vector_type(8))) short bf16x8;
typedef __attribute__((ext_vector_type(4))) float f32x4;

static __device__ __forceinline__ unsigned f2ord(float f) {
    unsigned b = __float_as_uint(f);
    return (b & 0x80000000u) ? ~b : (b | 0x80000000u);
}
static __device__ __forceinline__ float ord2f(unsigned u) {
    unsigned b = (u & 0x80000000u) ? (u ^ 0x80000000u) : ~u;
    return __uint_as_float(b);
}
static __device__ __forceinline__ unsigned short to_bf16(float f) {
    __hip_bfloat16 h = __float2bfloat16(f);
    return *(unsigned short*)&h;
}

// ---------------- kernel 1: e = codebook @ proj_w^T + proj_b  (fp32 exact) --
extern "C" __global__ __launch_bounds__(256)
void k_proj(const float* __restrict__ cb, const float* __restrict__ pw,
            const float* __restrict__ pb, float* __restrict__ e,
            unsigned short* __restrict__ eb)
{
    __shared__ __align__(16) float As[32][68];
    __shared__ __align__(16) float Bs[32][68];
    const int tid = threadIdx.x;
    const int tx = tid & 15, ty = tid >> 4;
    const int bm = blockIdx.x;
    const int bn = blockIdx.y;
    float acc[4][4] = {};

    float4 pva[2], pvb[2];
    auto issueP = [&](int k0) {
#pragma unroll
        for (int i = 0; i < 2; ++i) {
            int idx = tid + i * 256;
            int row = idx >> 3;
            int kg  = (idx & 7) << 2;
            pva[i] = *(const float4*)(cb + (size_t)(bm * 64 + row) * KDIM + k0 + kg);
            pvb[i] = *(const float4*)(pw + (size_t)(bn * 64 + row) * KDIM + k0 + kg);
        }
    };

    issueP(0);
    for (int k0 = 0; k0 < KDIM; k0 += 32) {
#pragma unroll
        for (int i = 0; i < 2; ++i) {          // commit regs -> LDS (transpose)
            int idx = tid + i * 256;
            int row = idx >> 3;
            int kg  = (idx & 7) << 2;
            As[kg + 0][row] = pva[i].x; As[kg + 1][row] = pva[i].y;
            As[kg + 2][row] = pva[i].z; As[kg + 3][row] = pva[i].w;
            Bs[kg + 0][row] = pvb[i].x; Bs[kg + 1][row] = pvb[i].y;
            Bs[kg + 2][row] = pvb[i].z; Bs[kg + 3][row] = pvb[i].w;
        }
        __syncthreads();
        if (k0 + 32 < KDIM) issueP(k0 + 32);   // overlap with compute below
#pragma unroll
        for (int k = 0; k < 32; ++k) {
            float4 a = *(const float4*)&As[k][ty * 4];
            float4 b = *(const float4*)&Bs[k][tx * 4];
            float av[4] = {a.x, a.y, a.z, a.w};
            float bv[4] = {b.x, b.y, b.z, b.w};
#pragma unroll
            for (int i = 0; i < 4; ++i)
#pragma unroll
                for (int j = 0; j < 4; ++j)
                    acc[i][j] = fmaf(av[i], bv[j], acc[i][j]);
        }
        __syncthreads();
    }
    const int col0 = bn * 64 + tx * 4;
    float4 bias = *(const float4*)(pb + col0);
    float bb[4] = {bias.x, bias.y, bias.z, bias.w};
#pragma unroll
    for (int i = 0; i < 4; ++i) {
        int row = bm * 64 + ty * 4 + i;
        float o[4];
#pragma unroll
        for (int j = 0; j < 4; ++j) o[j] = acc[i][j] + bb[j];
        *(float4*)(e + (size_t)row * CDIM + col0) = make_float4(o[0], o[1], o[2], o[3]);
        ushort4 ob;
        ob.x = to_bf16(o[0]); ob.y = to_bf16(o[1]);
        ob.z = to_bf16(o[2]); ob.w = to_bf16(o[3]);
        *(ushort4*)(eb + (size_t)row * CDIM + col0) = ob;
    }
}

// ---------------- kernel 1b: ||e_j||^2 ----------------
extern "C" __global__ __launch_bounds__(256)
void k_enorm(const float* __restrict__ e, float* __restrict__ en)
{
    int code = blockIdx.x * 4 + (threadIdx.x >> 6);
    int lane = threadIdx.x & 63;
    float4 v = *(const float4*)(e + (size_t)code * CDIM + lane * 4);
    float s = v.x * v.x + v.y * v.y + v.z * v.z + v.w * v.w;
#pragma unroll
    for (int off = 1; off < 64; off <<= 1) s += __shfl_xor(s, off);
    if (lane == 0) en[code] = s;
}

// ---------------- kernel 1d: z -> bf16 + zero cnt (merged init) -------------
extern "C" __global__ __launch_bounds__(256)
void k_cvtz(const float* __restrict__ z, unsigned short* __restrict__ zb,
            unsigned* __restrict__ cnt)
{
    size_t i = (size_t)blockIdx.x * 256 + threadIdx.x;   // 16 floats / thread
    if (i < NROWS) cnt[i] = 0u;
    const float4* src = (const float4*)(z + i * 16);
    unsigned short o[16];
#pragma unroll
    for (int q = 0; q < 4; ++q) {
        float4 v = src[q];
        o[q * 4 + 0] = to_bf16(v.x); o[q * 4 + 1] = to_bf16(v.y);
        o[q * 4 + 2] = to_bf16(v.z); o[q * 4 + 3] = to_bf16(v.w);
    }
    *(uint4*)(zb + i * 16)     = *(const uint4*)&o[0];   // 16 B
    *(uint4*)(zb + i * 16 + 8) = *(const uint4*)&o[8];   // 16 B
}

// ---------------- kernel 2: bf16 MFMA score + block argmin + candidates -----
// EXACT r12 structure (226 us proven: 128x128 tile, grid (32,256) bC-fast,
// 33,280B LDS, 4 blk/CU, gload_lds + vmcnt(0)-drain __syncthreads) + ONE
// change: K-QUARTER STAGGER.  Co-resident blocks (consecutive bC) start at
// different quarters (q = (bC&3 + qi) & 3), breaking the phase-lock where
// all 4 blocks/CU drain loads at the same instant -- one block's L2 drain
// now overlaps its neighbors' ds_read+MFMA phases.  K-sum order-invariant
// (rounding shifts << MARGIN; rerank exact).
extern "C" __global__ __launch_bounds__(256, 4)
void k_dist(const unsigned short* __restrict__ zb, const unsigned short* __restrict__ eb,
            const float* __restrict__ en, unsigned* __restrict__ cnt,
            unsigned* __restrict__ cand)
{
    __shared__ __align__(16) char lds[32768];     // As 16KB | Bs 16KB
    __shared__ unsigned rowmin[128];
    const int tid  = threadIdx.x;
    const int wave = tid >> 6, lane = tid & 63;
    const int bC = blockIdx.x, bR = blockIdx.y;   // grid (32, 256), bC fast
    const int wr = wave >> 1, wc = wave & 1;      // 2x2 waves, 64x64 out each
    const int fr = lane & 15;                     // A row / B col within frag
    const int kg = (lane >> 4) << 3;              // k sub-offset: 0,8,16,24
    const int qs = bC & 3;                        // per-block quarter stagger
    if (tid < 128) rowmin[tid] = 0xFFFFFFFFu;

    char* As = lds;
    char* Bs = lds + 16384;
    const char* gz = (const char*)zb + (size_t)bR * 128 * 512;  // row = 512B
    const char* ge = (const char*)eb + (size_t)bC * 128 * 512;

    // epilogue constants prefetched early
    const int colg0 = bC * 128 + wc * 64;
    float env[4];
#pragma unroll
    for (int ni = 0; ni < 4; ++ni) env[ni] = en[colg0 + ni * 16 + fr];

    f32x4 acc[4][4] = {};

    for (int qi = 0; qi < 4; ++qi) {              // staggered K quarters
        const int q = (qs + qi) & 3;              // k in [q*64, q*64+64)
#pragma unroll
        for (int i = 0; i < 4; ++i) {
            int chunk = tid + i * 256;            // [0,1024) 16B chunks
            int r  = chunk >> 3;                  // LDS/global row
            int wb = (chunk & 7) << 4;            // linear byte in 128B row
            int sw = wb ^ ((r & 7) << 4);         // inverse-swizzled source
            const char* gA = gz + (size_t)r * 512 + q * 128 + sw;
            const char* gB = ge + (size_t)r * 512 + q * 128 + sw;
            char* lA = As + i * 4096 + wave * 1024;   // wave-uniform base
            char* lB = Bs + i * 4096 + wave * 1024;
            __builtin_amdgcn_global_load_lds(
                (const __attribute__((address_space(1))) unsigned int*)gA,
                (__attribute__((address_space(3))) unsigned int*)lA, 16, 0, 0);
            __builtin_amdgcn_global_load_lds(
                (const __attribute__((address_space(1))) unsigned int*)gB,
                (__attribute__((address_space(3))) unsigned int*)lB, 16, 0, 0);
        }
        __syncthreads();   // drains vmcnt(0) before s_barrier
#pragma unroll
        for (int ks = 0; ks < 2; ++ks) {
            const int kb = (ks * 32 + kg) * 2;    // byte offset in 128B row
            bf16x8 a[4], b[4];
#pragma unroll
            for (int mi = 0; mi < 4; ++mi) {
                int row = wr * 64 + mi * 16 + fr;
                a[mi] = *(const bf16x8*)(As + row * 128 + (kb ^ ((row & 7) << 4)));
            }
#pragma unroll
            for (int ni = 0; ni < 4; ++ni) {
                int row = wc * 64 + ni * 16 + fr;
                b[ni] = *(const bf16x8*)(Bs + row * 128 + (kb ^ ((row & 7) << 4)));
            }
#pragma unroll
            for (int mi = 0; mi < 4; ++mi)
#pragma unroll
                for (int ni = 0; ni < 4; ++ni)
                    acc[mi][ni] = __builtin_amdgcn_mfma_f32_16x16x32_bf16(
                        a[mi], b[ni], acc[mi][ni], 0, 0, 0);
        }
        __syncthreads();
    }

    // ---- epilogue: d~ = en[col] - 2*s ; block-local row minima ----
#pragma unroll
    for (int mi = 0; mi < 4; ++mi)
#pragma unroll
        for (int ni = 0; ni < 4; ++ni)
#pragma unroll
            for (int j = 0; j < 4; ++j)
                acc[mi][ni][j] = fmaf(-2.0f, acc[mi][ni][j], env[ni]);

#pragma unroll
    for (int mi = 0; mi < 4; ++mi) {
#pragma unroll
        for (int j = 0; j < 4; ++j) {
            unsigned best = 0xFFFFFFFFu;
#pragma unroll
            for (int ni = 0; ni < 4; ++ni) {
                unsigned o = f2ord(acc[mi][ni][j]);
                best = o < best ? o : best;
            }
#pragma unroll
            for (int off = 8; off >= 1; off >>= 1) {
                unsigned o = __shfl_xor(best, off);
                best = o < best ? o : best;
            }
            if (fr == 0) {
                int rl = wr * 64 + mi * 16 + ((lane >> 4) << 2) + j;
                atomicMin(&rowmin[rl], best);
            }
        }
    }
    __syncthreads();

    // ---- emission: every col within MARGIN of block-local row min.
    //      NaN-safe: !(x > thr) is TRUE for NaN -> mass-emit -> fallback.
#pragma unroll
    for (int mi = 0; mi < 4; ++mi) {
#pragma unroll
        for (int j = 0; j < 4; ++j) {
            int rl = wr * 64 + mi * 16 + ((lane >> 4) << 2) + j;
            float thr = ord2f(rowmin[rl]) + MARGIN;
#pragma unroll
            for (int ni = 0; ni < 4; ++ni) {
                if (!(acc[mi][ni][j] > thr)) {
                    int rg = bR * 128 + rl;
                    unsigned slot = atomicAdd(&cnt[rg], 1u);
                    if (slot < NSLOT)
                        cand[(size_t)rg * NSLOT + slot] =
                            (unsigned)(colg0 + ni * 16 + fr);
                }
            }
        }
    }
}

// ---------------- kernel 3: exact re-rank, 4 candidates in parallel ---------
extern "C" __global__ __launch_bounds__(256)
void k_rerank(const float* __restrict__ z, const float* __restrict__ e,
              const float* __restrict__ en, const unsigned* __restrict__ cnt,
              const unsigned* __restrict__ cand, unsigned* __restrict__ outidx)
{
    int row  = blockIdx.x * 4 + (threadIdx.x >> 6);
    int lane = threadIdx.x & 63;
    int g    = lane >> 4;           // which of the 4 parallel candidates
    int sl   = lane & 15;           // sub-lane: dims [sl*16, sl*16+16)
    const float* zp = z + (size_t)row * CDIM + sl * 16;
    float4 zv[4];
#pragma unroll
    for (int t = 0; t < 4; ++t) zv[t] = *(const float4*)(zp + t * 4);
    unsigned n = cnt[row];
    double best_d2 = 1e300;
    unsigned best_col = 0u;

    auto eval4 = [&](unsigned col, bool valid) {
        const float* ep = e + (size_t)col * CDIM + sl * 16;
        double dot = 0.0;
#pragma unroll
        for (int t = 0; t < 4; ++t) {
            float4 ev = *(const float4*)(ep + t * 4);
            dot += (double)zv[t].x * ev.x + (double)zv[t].y * ev.y
                 + (double)zv[t].z * ev.z + (double)zv[t].w * ev.w;
        }
#pragma unroll
        for (int off = 1; off < 16; off <<= 1) dot += __shfl_xor(dot, off);
        double d2 = valid ? ((double)en[col] - 2.0 * dot) : 1e300;
#pragma unroll
        for (int off = 16; off <= 32; off <<= 1) {
            double od2    = __shfl_xor(d2, off);
            unsigned ocol = (unsigned)__shfl_xor((int)col, off);
            if (od2 < d2 || (od2 == d2 && ocol < col)) { d2 = od2; col = ocol; }
        }
        if (d2 < best_d2 || (d2 == best_d2 && col < best_col)) {
            best_d2 = d2; best_col = col;
        }
    };

    if (n >= 1u && n <= (unsigned)NSLOT) {
        for (unsigned i = 0; i < n; i += 4) {
            unsigned ii = i + (unsigned)g;
            bool valid = ii < n;
            unsigned col = valid ? (cand[(size_t)row * NSLOT + ii] & (NCODE - 1)) : 0u;
            eval4(col, valid);
        }
    } else {
        for (unsigned c0 = 0; c0 < NCODE; c0 += 4)
            eval4(c0 + (unsigned)g, true);
    }
    if (lane == 0) outidx[row] = best_col;
}

// ---------------- kernel 4: zidx + quant gather (overwrites ALL of d_out) ---
extern "C" __global__ __launch_bounds__(256)
void k_out(const unsigned* __restrict__ outidx, const float* __restrict__ e,
           float* __restrict__ out)
{
    int row  = blockIdx.x * 4 + (threadIdx.x >> 6);
    int lane = threadIdx.x & 63;
    unsigned idx = outidx[row] & (NCODE - 1);
    if (lane == 0) out[row] = (float)idx;
    float4 v = *(const float4*)(e + (size_t)idx * CDIM + lane * 4);
    *(float4*)(out + NROWS + (size_t)row * CDIM + lane * 4) = v;
}

extern "C" void kernel_launch(void* const* d_in, const int* in_sizes, int n_in,
                              void* d_out, int out_size, void* d_ws, size_t ws_size,
                              hipStream_t stream)
{
    const float* encode = (const float*)d_in[0];   // 32768 x 256
    const float* cb     = (const float*)d_in[1];   // 4096 x 1024
    const float* pw     = (const float*)d_in[2];   // 256 x 1024
    const float* pb     = (const float*)d_in[3];   // 256
    float* out = (float*)d_out;

    // ws: only what k_rerank/k_out read while d_out is being rewritten.
    char* ws = (char*)d_ws;
    float*    e      = (float*)(ws);                                  // 4 MiB
    float*    en     = (float*)(ws + (4u << 20));                     // 16 KiB
    unsigned* cnt    = (unsigned*)(ws + (4u << 20) + (16u << 10));    // 128 KiB
    unsigned* outidx = (unsigned*)(ws + (4u << 20) + (144u << 10));   // 128 KiB

    // Big transients in d_out's quant region (scratch until k_out's final
    // full overwrite; nothing reads them after k_rerank).
    char* S = (char*)(out + NROWS);
    unsigned short* zb   = (unsigned short*)(S);               // 16 MiB
    unsigned short* eb   = (unsigned short*)(S + (16u << 20)); // 2 MiB
    unsigned*       cand = (unsigned*)(S + (18u << 20));       // 12 MiB (ends 30 MiB)

    k_proj  <<<dim3(64, 4),   256, 0, stream>>>(cb, pw, pb, e, eb);
    k_enorm <<<dim3(1024),    256, 0, stream>>>(e, en);
    k_cvtz  <<<dim3(2048),    256, 0, stream>>>(encode, zb, cnt);
    k_dist  <<<dim3(32, 256), 256, 0, stream>>>(zb, eb, en, cnt, cand);
    k_rerank<<<dim3(8192),    256, 0, stream>>>(encode, e, en, cnt, cand, outidx);
    k_out   <<<dim3(8192),    256, 0, stream>>>(outidx, e, out);
}